// Round 3
// 219.244 us; speedup vs baseline: 1.0211x; 1.0211x over previous
//
#include <hip/hip_runtime.h>

typedef unsigned short ushort_t;
typedef __attribute__((ext_vector_type(8))) short bf16x8;
typedef __attribute__((ext_vector_type(4))) float f32x4v;

#define EPB 8000   // edges per sort block (round-0 proven config)

static __device__ __forceinline__ float bf2f(ushort_t u) {
  union { unsigned int i; float f; } v; v.i = ((unsigned int)u) << 16; return v.f;
}
static __device__ __forceinline__ ushort_t f2bf(float f) {
  union { float f; unsigned int i; } v; v.f = f;
  unsigned int r = v.i + 0x7FFFu + ((v.i >> 16) & 1u);
  return (ushort_t)(r >> 16);
}
static __device__ __forceinline__ float leaky(float s) {
  return s > 0.f ? s : 0.2f * s;
}

// ---------------------------------------------------------------------------
// FUSED: block nb3 packs W_ext into B-fragments; blocks 0..nb3-1 do the
// coarse-bucket histogram.
// ---------------------------------------------------------------------------
__global__ __launch_bounds__(256) void packw_hist(
    const float* __restrict__ W, const float* __restrict__ attnl,
    const float* __restrict__ attnr, ushort_t* __restrict__ wfrag,
    const int* __restrict__ trg, int E, int nbkt,
    int* __restrict__ blockHist, int nb3)
{
  const int b = blockIdx.x;
  const int t = threadIdx.x;
  if (b == nb3) {
    const int kc = t >> 6, l = t & 63;
    const int q = l >> 4, n = l & 15;
    #pragma unroll
    for (int tile = 0; tile < 5; ++tile) {
      #pragma unroll
      for (int j = 0; j < 8; ++j) {
        const int k = kc * 32 + q * 8 + j;
        float v = 0.f;
        if (tile < 4) {
          v = W[k * 64 + tile * 16 + n];
        } else if (n < 4) {
          for (int f = 0; f < 16; ++f)
            v += W[k * 64 + n * 16 + f] * attnl[n * 16 + f];
        } else if (n < 8) {
          const int hd = n - 4;
          for (int f = 0; f < 16; ++f)
            v += W[k * 64 + hd * 16 + f] * attnr[hd * 16 + f];
        }
        wfrag[((tile * 4 + kc) * 64 + l) * 8 + j] = f2bf(v);
      }
    }
    return;
  }
  __shared__ int hist[256];
  hist[t] = 0;
  __syncthreads();
  const int start = b * EPB;
  const int end = min(start + EPB, E);
  for (int e = start + t; e < end; e += 256)
    atomicAdd(&hist[trg[e] >> 9], 1);
  __syncthreads();
  if (t < nbkt) blockHist[b * nbkt + t] = hist[t];
}

// ---------------------------------------------------------------------------
// Per-bucket column scan of blockHist -> in-place exclusive prefix + total.
// ---------------------------------------------------------------------------
__global__ __launch_bounds__(64) void bucket_scan(
    int* __restrict__ blockHist, int nb3, int nbkt, int* __restrict__ colTotal)
{
  const int b = blockIdx.x;
  const int l = threadIdx.x;
  int carry = 0;
  for (int r = 0; r * 64 < nb3; ++r) {
    const int i = r * 64 + l;
    int v = (i < nb3) ? blockHist[i * nbkt + b] : 0;
    int incl = v;
    #pragma unroll
    for (int d = 1; d < 64; d <<= 1) {
      int u = __shfl_up(incl, d, 64);
      if (l >= d) incl += u;
    }
    if (i < nb3) blockHist[i * nbkt + b] = carry + incl - v;
    carry += __shfl(incl, 63, 64);
  }
  if (l == 0) colTotal[b] = carry;
}

// ---------------------------------------------------------------------------
// Scan colTotal -> bucketBase; rowoff[N]=E.
// ---------------------------------------------------------------------------
__global__ __launch_bounds__(64) void bucket_base(
    const int* __restrict__ colTotal, int nbkt, int* __restrict__ bucketBase,
    int* __restrict__ rowoff, int N, int E)
{
  const int l = threadIdx.x;
  int carry = 0;
  for (int r = 0; r * 64 < nbkt; ++r) {
    const int i = r * 64 + l;
    int v = (i < nbkt) ? colTotal[i] : 0;
    int incl = v;
    #pragma unroll
    for (int d = 1; d < 64; d <<= 1) {
      int u = __shfl_up(incl, d, 64);
      if (l >= d) incl += u;
    }
    if (i < nbkt) bucketBase[i] = carry + incl - v;
    carry += __shfl(incl, 63, 64);
  }
  if (l == 0) { bucketBase[nbkt] = carry; rowoff[N] = E; }
}

// ---------------------------------------------------------------------------
// Deterministic coarse scatter (no global atomics); payload (src<<9)|localTrg.
// ---------------------------------------------------------------------------
__global__ __launch_bounds__(256) void bucket_scatter(
    const int* __restrict__ src, const int* __restrict__ trg, int E, int nbkt,
    const int* __restrict__ blockHist, const int* __restrict__ bucketBase,
    unsigned int* __restrict__ binned)
{
  __shared__ int cursor[256];
  const int t = threadIdx.x, b = blockIdx.x;
  if (t < nbkt) cursor[t] = bucketBase[t] + blockHist[b * nbkt + t];
  __syncthreads();
  const int start = b * EPB;
  const int end = min(start + EPB, E);
  for (int e = start + t; e < end; e += 256) {
    const int ti = trg[e];
    const int bkt = ti >> 9;
    const int pos = atomicAdd(&cursor[bkt], 1);
    binned[pos] = ((unsigned int)src[e] << 9) | (unsigned int)(ti & 511);
  }
}

// ---------------------------------------------------------------------------
// Kernel A (MFMA): h_ext = feat @ W_ext. 64 nodes/block; wave w owns nodes
// w*16..w*16+15 across all 5 col-tiles. feat staged bf16 in LDS (pad 136).
// Tile 4 yields el/er directly in C-layout -> no shuffle reductions.
// ---------------------------------------------------------------------------
__global__ __launch_bounds__(256) void gat_linear(
    const float* __restrict__ feat, const ushort_t* __restrict__ wfrag,
    ushort_t* __restrict__ h_out, float* __restrict__ el, float* __restrict__ er,
    float* __restrict__ blockmax2, int N)
{
  __shared__ ushort_t sFb[64 * 136];   // 17.4 KB
  __shared__ float wmax[8];
  const int t = threadIdx.x;
  const int b = blockIdx.x;
  const int w = t >> 6, l = t & 63;
  const int q = l >> 4, m = l & 15;

  // stage feat (64 x 128 fp32 -> bf16), coalesced float4 loads
  const float4* gF = (const float4*)(feat + (size_t)b * 64 * 128);
  #pragma unroll
  for (int i = 0; i < 8; ++i) {
    const int idx = i * 256 + t;
    const int node = idx >> 5, off = idx & 31;
    float4 v = make_float4(0.f, 0.f, 0.f, 0.f);
    if (b * 64 + node < N) v = gF[idx];
    unsigned int p0 = ((unsigned int)f2bf(v.y) << 16) | f2bf(v.x);
    unsigned int p1 = ((unsigned int)f2bf(v.w) << 16) | f2bf(v.z);
    *(uint2*)(sFb + node * 136 + off * 4) = make_uint2(p0, p1);
  }
  __syncthreads();

  // A-fragments: 4 K-chunks, one ds_read_b128 each
  bf16x8 a[4];
  const ushort_t* arow = sFb + (w * 16 + m) * 136 + q * 8;
  #pragma unroll
  for (int kc = 0; kc < 4; ++kc)
    a[kc] = *(const bf16x8*)(arow + kc * 32);

  // tiles 0..3: h columns
  #pragma unroll
  for (int tile = 0; tile < 4; ++tile) {
    f32x4v acc = {0.f, 0.f, 0.f, 0.f};
    #pragma unroll
    for (int kc = 0; kc < 4; ++kc) {
      bf16x8 bfr = *(const bf16x8*)(wfrag + ((tile * 4 + kc) * 64 + l) * 8);
      acc = __builtin_amdgcn_mfma_f32_16x16x32_bf16(a[kc], bfr, acc, 0, 0, 0);
    }
    #pragma unroll
    for (int r = 0; r < 4; ++r) {
      const int gn = b * 64 + w * 16 + q * 4 + r;
      if (gn < N) h_out[(size_t)gn * 64 + tile * 16 + m] = f2bf(acc[r]);
    }
  }

  // tile 4: el (cols 0-3) / er (cols 4-7)
  f32x4v acc4 = {0.f, 0.f, 0.f, 0.f};
  #pragma unroll
  for (int kc = 0; kc < 4; ++kc) {
    bf16x8 bfr = *(const bf16x8*)(wfrag + ((4 * 4 + kc) * 64 + l) * 8);
    acc4 = __builtin_amdgcn_mfma_f32_16x16x32_bf16(a[kc], bfr, acc4, 0, 0, 0);
  }
  float mel = -1e30f, mer = -1e30f;
  #pragma unroll
  for (int r = 0; r < 4; ++r) {
    const int gn = b * 64 + w * 16 + q * 4 + r;
    const float v = acc4[r];
    if (m < 4) {
      if (gn < N) el[gn * 4 + m] = v;
      mel = fmaxf(mel, v);
    } else if (m < 8) {
      if (gn < N) er[gn * 4 + (m - 4)] = v;
      mer = fmaxf(mer, v);
    }
  }
  #pragma unroll
  for (int o = 1; o <= 32; o <<= 1) {
    mel = fmaxf(mel, __shfl_xor(mel, o, 64));
    mer = fmaxf(mer, __shfl_xor(mer, o, 64));
  }
  if (l == 0) { wmax[w * 2] = mel; wmax[w * 2 + 1] = mer; }
  __syncthreads();
  if (t == 0) {
    float aa = fmaxf(fmaxf(wmax[0], wmax[2]), fmaxf(wmax[4], wmax[6]));
    float cc = fmaxf(fmaxf(wmax[1], wmax[3]), fmaxf(wmax[5], wmax[7]));
    blockmax2[b * 2] = aa;
    blockmax2[b * 2 + 1] = cc;
  }
}

// ---------------------------------------------------------------------------
// Fine sort (one block per bucket) + block 0 reduces blockmax2 -> gmaxM.
// ---------------------------------------------------------------------------
__global__ __launch_bounds__(512) void fine_scatter(
    const unsigned int* __restrict__ binned, const int* __restrict__ bucketBase,
    int* __restrict__ rowoff, int* __restrict__ csrsrc, int N,
    const float* __restrict__ blockmax2, int nbL, float* __restrict__ gmaxM)
{
  __shared__ int cnt[512];
  __shared__ int ws[8];
  __shared__ float wmg[16];
  const int t = threadIdx.x, b = blockIdx.x;
  const int l = t & 63, w = t >> 6;
  const int base = bucketBase[b];
  const int end = bucketBase[b + 1];
  cnt[t] = 0;
  if (b == 0) {
    float mel = -1e30f, mer = -1e30f;
    for (int i = t; i < nbL; i += 512) {
      mel = fmaxf(mel, blockmax2[i * 2]);
      mer = fmaxf(mer, blockmax2[i * 2 + 1]);
    }
    #pragma unroll
    for (int o = 1; o <= 32; o <<= 1) {
      mel = fmaxf(mel, __shfl_xor(mel, o, 64));
      mer = fmaxf(mer, __shfl_xor(mer, o, 64));
    }
    if (l == 0) { wmg[w * 2] = mel; wmg[w * 2 + 1] = mer; }
  }
  __syncthreads();
  if (b == 0 && t == 0) {
    float aa = -1e30f, cc = -1e30f;
    for (int i = 0; i < 8; ++i) {
      aa = fmaxf(aa, wmg[i * 2]);
      cc = fmaxf(cc, wmg[i * 2 + 1]);
    }
    gmaxM[0] = fmaxf(0.f, aa + cc);
  }
  for (int i = base + t; i < end; i += 512)
    atomicAdd(&cnt[binned[i] & 511u], 1);
  __syncthreads();
  const int v = cnt[t];
  int incl = v;
  #pragma unroll
  for (int d = 1; d < 64; d <<= 1) {
    int u = __shfl_up(incl, d, 64);
    if (l >= d) incl += u;
  }
  if (l == 63) ws[w] = incl;
  __syncthreads();
  int woff = 0;
  for (int i = 0; i < w; ++i) woff += ws[i];
  const int loc = woff + incl - v;
  cnt[t] = loc;
  const int gt = b * 512 + t;
  if (gt < N) rowoff[gt] = base + loc;
  __syncthreads();
  for (int i = base + t; i < end; i += 512) {
    const unsigned int pv = binned[i];
    const int lt = (int)(pv & 511u);
    const int pos = base + atomicAdd(&cnt[lt], 1);
    csrsrc[pos] = (int)(pv >> 9);
  }
}

// ---------------------------------------------------------------------------
// Aggregation: one wave per target node. Lane l owns feats (l&7)*8..+7 of
// edge-row group l>>3. One global_load_dwordx4 gathers EIGHT h-rows per
// instruction (1 KB/wave) instead of one row per ushort load. Two octets in
// flight per iteration. p and src staged in per-wave LDS; rows >= cnt carry
// p=0 so no tail branches.
// ---------------------------------------------------------------------------
#define FMA8(hv, p) do { \
  union { unsigned int i; float f; } c_; \
  c_.i = (hv).x << 16;          a0 += c_.f * (p); \
  c_.i = (hv).x & 0xffff0000u;  a1 += c_.f * (p); \
  c_.i = (hv).y << 16;          a2 += c_.f * (p); \
  c_.i = (hv).y & 0xffff0000u;  a3 += c_.f * (p); \
  c_.i = (hv).z << 16;          a4 += c_.f * (p); \
  c_.i = (hv).z & 0xffff0000u;  a5 += c_.f * (p); \
  c_.i = (hv).w << 16;          a6 += c_.f * (p); \
  c_.i = (hv).w & 0xffff0000u;  a7 += c_.f * (p); \
} while (0)

__global__ __launch_bounds__(256) void gat_agg(
    const int* __restrict__ csrsrc, const int* __restrict__ rowoff,
    const float4* __restrict__ el4, const float4* __restrict__ er4,
    const ushort_t* __restrict__ hbf, const float* __restrict__ gmaxM,
    float* __restrict__ out, int N)
{
  __shared__ float sP[4 * 64 * 4];
  __shared__ int sS[4 * 64];
  const int t = threadIdx.x;
  const int l = t & 63;
  const int w = t >> 6;
  const int n = blockIdx.x * 4 + w;
  if (n >= N) return;
  const int rg = l >> 3;        // row group: which of 8 edge-rows I help load
  const int cg = l & 7;         // col group: feats cg*8..cg*8+7
  const int hd2 = cg >> 1;      // head of those 8 feats (never crosses a head)
  const int start = rowoff[n];
  const int end = rowoff[n + 1];
  const float M = gmaxM[0];
  const float4 ern = er4[n];
  float* sPw = sP + w * 256;
  int* sSw = sS + w * 64;
  const ushort_t* hcg = hbf + cg * 8;   // my 16B slice of any row

  float a0 = 0.f, a1 = 0.f, a2 = 0.f, a3 = 0.f;
  float a4 = 0.f, a5 = 0.f, a6 = 0.f, a7 = 0.f;
  float4 dsum = make_float4(0.f, 0.f, 0.f, 0.f);

  for (int base = start; base < end; base += 64) {
    const int cnt = min(64, end - base);
    int sn = 0;
    float4 pv = make_float4(0.f, 0.f, 0.f, 0.f);
    if (l < cnt) {
      sn = csrsrc[base + l];
      const float4 a = el4[sn];
      pv.x = __expf(leaky(a.x + ern.x) - M);
      pv.y = __expf(leaky(a.y + ern.y) - M);
      pv.z = __expf(leaky(a.z + ern.z) - M);
      pv.w = __expf(leaky(a.w + ern.w) - M);
    }
    dsum.x += pv.x; dsum.y += pv.y; dsum.z += pv.z; dsum.w += pv.w;
    *(float4*)(sPw + l * 4) = pv;   // lanes >= cnt store p=0 (kills pad rows)
    sSw[l] = sn;                    // lanes >= cnt store row 0 (harmless, p=0)

    // two octets (16 edge-rows) per iteration -> 2 dwordx4 gathers in flight
    for (int j = 0; j < cnt; j += 16) {
      const int sA = sSw[j + rg];
      const int sB = sSw[j + 8 + rg];          // always < 64, p=0 past cnt
      const float pA = sPw[(j + rg) * 4 + hd2];
      const float pB = sPw[(j + 8 + rg) * 4 + hd2];
      const uint4 hA = *(const uint4*)(hcg + (size_t)sA * 64);
      const uint4 hB = *(const uint4*)(hcg + (size_t)sB * 64);
      FMA8(hA, pA);
      FMA8(hB, pB);
    }
  }

  // combine the 8 row-group partials (lanes l, l^8, l^16, l^32 share feats)
  #pragma unroll
  for (int o = 8; o <= 32; o <<= 1) {
    a0 += __shfl_xor(a0, o, 64); a1 += __shfl_xor(a1, o, 64);
    a2 += __shfl_xor(a2, o, 64); a3 += __shfl_xor(a3, o, 64);
    a4 += __shfl_xor(a4, o, 64); a5 += __shfl_xor(a5, o, 64);
    a6 += __shfl_xor(a6, o, 64); a7 += __shfl_xor(a7, o, 64);
  }
  #pragma unroll
  for (int o = 1; o <= 32; o <<= 1) {
    dsum.x += __shfl_xor(dsum.x, o, 64);
    dsum.y += __shfl_xor(dsum.y, o, 64);
    dsum.z += __shfl_xor(dsum.z, o, 64);
    dsum.w += __shfl_xor(dsum.w, o, 64);
  }
  if (rg == 0) {   // lanes 0..7 write 32B each -> 256B contiguous per wave
    const float d = (hd2 == 0) ? dsum.x : (hd2 == 1) ? dsum.y
                  : (hd2 == 2) ? dsum.z : dsum.w;
    const float r = 1.0f / (d + 1e-16f);
    float4* orow = (float4*)(out + (size_t)n * 64 + cg * 8);
    orow[0] = make_float4(a0 * r, a1 * r, a2 * r, a3 * r);
    orow[1] = make_float4(a4 * r, a5 * r, a6 * r, a7 * r);
  }
}

// ---------------------------------------------------------------------------
extern "C" void kernel_launch(void* const* d_in, const int* in_sizes, int n_in,
                              void* d_out, int out_size, void* d_ws, size_t ws_size,
                              hipStream_t stream) {
  const float* feat  = (const float*)d_in[0];
  const float* W     = (const float*)d_in[1];
  const float* attnl = (const float*)d_in[2];
  const float* attnr = (const float*)d_in[3];
  const int* src = (const int*)d_in[4];
  const int* trg = (const int*)d_in[5];
  float* out = (float*)d_out;

  const int N = in_sizes[0] / 128;  // 100000
  const int E = in_sizes[4];        // 1600000

  const int nbL  = (N + 63) / 64;        // 1563 linear blocks
  const int nbkt = (N + 511) >> 9;       // 196 coarse buckets
  const int nb3  = (E + EPB - 1) / EPB;  // 200 sort blocks

  char* p = (char*)d_ws;
  auto take = [&](size_t bytes) -> char* {
    char* r = p;
    p += (bytes + 255) & ~(size_t)255;
    return r;
  };
  ushort_t* h_bf  = (ushort_t*)take((size_t)N * 64 * 2); // 12.8 MB
  float* el       = (float*)take((size_t)N * 16);        // 1.6 MB
  float* er       = (float*)take((size_t)N * 16);        // 1.6 MB
  int* rowoff     = (int*)take((size_t)(N + 1) * 4);
  int* csrsrc     = (int*)take((size_t)E * 4);           // 6.4 MB
  unsigned int* binned = (unsigned int*)take((size_t)E * 4); // 6.4 MB
  ushort_t* wfrag = (ushort_t*)take(5 * 4 * 64 * 8 * 2); // 20.5 KB
  int* blockHist  = (int*)take((size_t)nb3 * nbkt * 4);  // 157 KB
  int* colTotal   = (int*)take((size_t)nbkt * 4);
  int* bucketBase = (int*)take((size_t)(nbkt + 1) * 4);
  float* blockmax2 = (float*)take((size_t)nbL * 2 * 4);
  float* gmaxM    = (float*)take(256);

  packw_hist<<<nb3 + 1, 256, 0, stream>>>(W, attnl, attnr, wfrag,
                                          trg, E, nbkt, blockHist, nb3);
  bucket_scan<<<nbkt, 64, 0, stream>>>(blockHist, nb3, nbkt, colTotal);
  bucket_base<<<1, 64, 0, stream>>>(colTotal, nbkt, bucketBase, rowoff, N, E);
  bucket_scatter<<<nb3, 256, 0, stream>>>(src, trg, E, nbkt, blockHist,
                                          bucketBase, binned);
  gat_linear<<<nbL, 256, 0, stream>>>(feat, wfrag, h_bf, el, er,
                                      blockmax2, N);
  fine_scatter<<<nbkt, 512, 0, stream>>>(binned, bucketBase, rowoff, csrsrc,
                                         N, blockmax2, nbL, gmaxM);
  gat_agg<<<(N + 3) / 4, 256, 0, stream>>>(csrsrc, rowoff, (const float4*)el,
                                           (const float4*)er, h_bf,
                                           gmaxM, out, N);
}

// Round 4
// 204.246 us; speedup vs baseline: 1.0961x; 1.0734x over previous
//
#include <hip/hip_runtime.h>

typedef unsigned short ushort_t;
typedef __attribute__((ext_vector_type(8))) short bf16x8;
typedef __attribute__((ext_vector_type(4))) float f32x4v;

static __device__ __forceinline__ float bf2f(ushort_t u) {
  union { unsigned int i; float f; } v; v.i = ((unsigned int)u) << 16; return v.f;
}
static __device__ __forceinline__ ushort_t f2bf(float f) {
  union { float f; unsigned int i; } v; v.f = f;
  unsigned int r = v.i + 0x7FFFu + ((v.i >> 16) & 1u);
  return (ushort_t)(r >> 16);
}
static __device__ __forceinline__ float leaky(float s) {
  return s > 0.f ? s : 0.2f * s;
}

// ---------------------------------------------------------------------------
// FUSED: block nb3 packs W_ext into B-fragments; blocks 0..nb3-1 do the
// coarse-bucket histogram. epb is runtime (workspace-sized).
// ---------------------------------------------------------------------------
__global__ __launch_bounds__(256) void packw_hist(
    const float* __restrict__ W, const float* __restrict__ attnl,
    const float* __restrict__ attnr, ushort_t* __restrict__ wfrag,
    const int* __restrict__ trg, int E, int nbkt,
    int* __restrict__ blockHist, int nb3, int epb)
{
  const int b = blockIdx.x;
  const int t = threadIdx.x;
  if (b == nb3) {
    const int kc = t >> 6, l = t & 63;
    const int q = l >> 4, n = l & 15;
    #pragma unroll
    for (int tile = 0; tile < 5; ++tile) {
      #pragma unroll
      for (int j = 0; j < 8; ++j) {
        const int k = kc * 32 + q * 8 + j;
        float v = 0.f;
        if (tile < 4) {
          v = W[k * 64 + tile * 16 + n];
        } else if (n < 4) {
          for (int f = 0; f < 16; ++f)
            v += W[k * 64 + n * 16 + f] * attnl[n * 16 + f];
        } else if (n < 8) {
          const int hd = n - 4;
          for (int f = 0; f < 16; ++f)
            v += W[k * 64 + hd * 16 + f] * attnr[hd * 16 + f];
        }
        wfrag[((tile * 4 + kc) * 64 + l) * 8 + j] = f2bf(v);
      }
    }
    return;
  }
  __shared__ int hist[256];
  hist[t] = 0;
  __syncthreads();
  const int start = b * epb;
  const int end = min(start + epb, E);
  for (int e = start + t; e < end; e += 256)
    atomicAdd(&hist[trg[e] >> 9], 1);
  __syncthreads();
  if (t < nbkt) blockHist[b * nbkt + t] = hist[t];
}

// ---------------------------------------------------------------------------
// Per-bucket column scan of blockHist -> in-place exclusive prefix + total.
// ---------------------------------------------------------------------------
__global__ __launch_bounds__(64) void bucket_scan(
    int* __restrict__ blockHist, int nb3, int nbkt, int* __restrict__ colTotal)
{
  const int b = blockIdx.x;
  const int l = threadIdx.x;
  int carry = 0;
  for (int r = 0; r * 64 < nb3; ++r) {
    const int i = r * 64 + l;
    int v = (i < nb3) ? blockHist[i * nbkt + b] : 0;
    int incl = v;
    #pragma unroll
    for (int d = 1; d < 64; d <<= 1) {
      int u = __shfl_up(incl, d, 64);
      if (l >= d) incl += u;
    }
    if (i < nb3) blockHist[i * nbkt + b] = carry + incl - v;
    carry += __shfl(incl, 63, 64);
  }
  if (l == 0) colTotal[b] = carry;
}

// ---------------------------------------------------------------------------
// Scan colTotal -> bucketBase; rowoff[N]=E.
// ---------------------------------------------------------------------------
__global__ __launch_bounds__(64) void bucket_base(
    const int* __restrict__ colTotal, int nbkt, int* __restrict__ bucketBase,
    int* __restrict__ rowoff, int N, int E)
{
  const int l = threadIdx.x;
  int carry = 0;
  for (int r = 0; r * 64 < nbkt; ++r) {
    const int i = r * 64 + l;
    int v = (i < nbkt) ? colTotal[i] : 0;
    int incl = v;
    #pragma unroll
    for (int d = 1; d < 64; d <<= 1) {
      int u = __shfl_up(incl, d, 64);
      if (l >= d) incl += u;
    }
    if (i < nbkt) bucketBase[i] = carry + incl - v;
    carry += __shfl(incl, 63, 64);
  }
  if (l == 0) { bucketBase[nbkt] = carry; rowoff[N] = E; }
}

// ---------------------------------------------------------------------------
// Deterministic coarse scatter (no global atomics); payload (src<<9)|localTrg.
// ---------------------------------------------------------------------------
__global__ __launch_bounds__(256) void bucket_scatter(
    const int* __restrict__ src, const int* __restrict__ trg, int E, int nbkt,
    const int* __restrict__ blockHist, const int* __restrict__ bucketBase,
    unsigned int* __restrict__ binned, int epb)
{
  __shared__ int cursor[256];
  const int t = threadIdx.x, b = blockIdx.x;
  if (t < nbkt) cursor[t] = bucketBase[t] + blockHist[b * nbkt + t];
  __syncthreads();
  const int start = b * epb;
  const int end = min(start + epb, E);
  for (int e = start + t; e < end; e += 256) {
    const int ti = trg[e];
    const int bkt = ti >> 9;
    const int pos = atomicAdd(&cursor[bkt], 1);
    binned[pos] = ((unsigned int)src[e] << 9) | (unsigned int)(ti & 511);
  }
}

// ---------------------------------------------------------------------------
// Kernel A (MFMA): h_ext = feat @ W_ext. 64 nodes/block; wave w owns nodes
// w*16..w*16+15 across all 5 col-tiles. feat staged bf16 in LDS (pad 136).
// Tile 4 yields el/er directly in C-layout -> no shuffle reductions.
// ---------------------------------------------------------------------------
__global__ __launch_bounds__(256) void gat_linear(
    const float* __restrict__ feat, const ushort_t* __restrict__ wfrag,
    ushort_t* __restrict__ h_out, float* __restrict__ el, float* __restrict__ er,
    float* __restrict__ blockmax2, int N)
{
  __shared__ ushort_t sFb[64 * 136];   // 17.4 KB
  __shared__ float wmax[8];
  const int t = threadIdx.x;
  const int b = blockIdx.x;
  const int w = t >> 6, l = t & 63;
  const int q = l >> 4, m = l & 15;

  // stage feat (64 x 128 fp32 -> bf16), coalesced float4 loads
  const float4* gF = (const float4*)(feat + (size_t)b * 64 * 128);
  #pragma unroll
  for (int i = 0; i < 8; ++i) {
    const int idx = i * 256 + t;
    const int node = idx >> 5, off = idx & 31;
    float4 v = make_float4(0.f, 0.f, 0.f, 0.f);
    if (b * 64 + node < N) v = gF[idx];
    unsigned int p0 = ((unsigned int)f2bf(v.y) << 16) | f2bf(v.x);
    unsigned int p1 = ((unsigned int)f2bf(v.w) << 16) | f2bf(v.z);
    *(uint2*)(sFb + node * 136 + off * 4) = make_uint2(p0, p1);
  }
  __syncthreads();

  // A-fragments: 4 K-chunks, one ds_read_b128 each
  bf16x8 a[4];
  const ushort_t* arow = sFb + (w * 16 + m) * 136 + q * 8;
  #pragma unroll
  for (int kc = 0; kc < 4; ++kc)
    a[kc] = *(const bf16x8*)(arow + kc * 32);

  // tiles 0..3: h columns
  #pragma unroll
  for (int tile = 0; tile < 4; ++tile) {
    f32x4v acc = {0.f, 0.f, 0.f, 0.f};
    #pragma unroll
    for (int kc = 0; kc < 4; ++kc) {
      bf16x8 bfr = *(const bf16x8*)(wfrag + ((tile * 4 + kc) * 64 + l) * 8);
      acc = __builtin_amdgcn_mfma_f32_16x16x32_bf16(a[kc], bfr, acc, 0, 0, 0);
    }
    #pragma unroll
    for (int r = 0; r < 4; ++r) {
      const int gn = b * 64 + w * 16 + q * 4 + r;
      if (gn < N) h_out[(size_t)gn * 64 + tile * 16 + m] = f2bf(acc[r]);
    }
  }

  // tile 4: el (cols 0-3) / er (cols 4-7)
  f32x4v acc4 = {0.f, 0.f, 0.f, 0.f};
  #pragma unroll
  for (int kc = 0; kc < 4; ++kc) {
    bf16x8 bfr = *(const bf16x8*)(wfrag + ((4 * 4 + kc) * 64 + l) * 8);
    acc4 = __builtin_amdgcn_mfma_f32_16x16x32_bf16(a[kc], bfr, acc4, 0, 0, 0);
  }
  float mel = -1e30f, mer = -1e30f;
  #pragma unroll
  for (int r = 0; r < 4; ++r) {
    const int gn = b * 64 + w * 16 + q * 4 + r;
    const float v = acc4[r];
    if (m < 4) {
      if (gn < N) el[gn * 4 + m] = v;
      mel = fmaxf(mel, v);
    } else if (m < 8) {
      if (gn < N) er[gn * 4 + (m - 4)] = v;
      mer = fmaxf(mer, v);
    }
  }
  #pragma unroll
  for (int o = 1; o <= 32; o <<= 1) {
    mel = fmaxf(mel, __shfl_xor(mel, o, 64));
    mer = fmaxf(mer, __shfl_xor(mer, o, 64));
  }
  if (l == 0) { wmax[w * 2] = mel; wmax[w * 2 + 1] = mer; }
  __syncthreads();
  if (t == 0) {
    float aa = fmaxf(fmaxf(wmax[0], wmax[2]), fmaxf(wmax[4], wmax[6]));
    float cc = fmaxf(fmaxf(wmax[1], wmax[3]), fmaxf(wmax[5], wmax[7]));
    blockmax2[b * 2] = aa;
    blockmax2[b * 2 + 1] = cc;
  }
}

// ---------------------------------------------------------------------------
// Fine sort (one block per bucket) + block 0 reduces blockmax2 -> gmaxM.
// ---------------------------------------------------------------------------
__global__ __launch_bounds__(512) void fine_scatter(
    const unsigned int* __restrict__ binned, const int* __restrict__ bucketBase,
    int* __restrict__ rowoff, int* __restrict__ csrsrc, int N,
    const float* __restrict__ blockmax2, int nbL, float* __restrict__ gmaxM)
{
  __shared__ int cnt[512];
  __shared__ int ws[8];
  __shared__ float wmg[16];
  const int t = threadIdx.x, b = blockIdx.x;
  const int l = t & 63, w = t >> 6;
  const int base = bucketBase[b];
  const int end = bucketBase[b + 1];
  cnt[t] = 0;
  if (b == 0) {
    float mel = -1e30f, mer = -1e30f;
    for (int i = t; i < nbL; i += 512) {
      mel = fmaxf(mel, blockmax2[i * 2]);
      mer = fmaxf(mer, blockmax2[i * 2 + 1]);
    }
    #pragma unroll
    for (int o = 1; o <= 32; o <<= 1) {
      mel = fmaxf(mel, __shfl_xor(mel, o, 64));
      mer = fmaxf(mer, __shfl_xor(mer, o, 64));
    }
    if (l == 0) { wmg[w * 2] = mel; wmg[w * 2 + 1] = mer; }
  }
  __syncthreads();
  if (b == 0 && t == 0) {
    float aa = -1e30f, cc = -1e30f;
    for (int i = 0; i < 8; ++i) {
      aa = fmaxf(aa, wmg[i * 2]);
      cc = fmaxf(cc, wmg[i * 2 + 1]);
    }
    gmaxM[0] = fmaxf(0.f, aa + cc);
  }
  for (int i = base + t; i < end; i += 512)
    atomicAdd(&cnt[binned[i] & 511u], 1);
  __syncthreads();
  const int v = cnt[t];
  int incl = v;
  #pragma unroll
  for (int d = 1; d < 64; d <<= 1) {
    int u = __shfl_up(incl, d, 64);
    if (l >= d) incl += u;
  }
  if (l == 63) ws[w] = incl;
  __syncthreads();
  int woff = 0;
  for (int i = 0; i < w; ++i) woff += ws[i];
  const int loc = woff + incl - v;
  cnt[t] = loc;
  const int gt = b * 512 + t;
  if (gt < N) rowoff[gt] = base + loc;
  __syncthreads();
  for (int i = base + t; i < end; i += 512) {
    const unsigned int pv = binned[i];
    const int lt = (int)(pv & 511u);
    const int pos = base + atomicAdd(&cnt[lt], 1);
    csrsrc[pos] = (int)(pv >> 9);
  }
}

// ---------------------------------------------------------------------------
// Aggregation: one wave per target node. Lane l owns feats (l&7)*8..+7 of
// edge-row group l>>3; one dwordx4 gathers 8 h-rows per instruction.
// NEW: softmax denominator rides as a 9th accumulator (a8 += p) through the
// SAME 3 xor-reduction rounds as a0..a7 -> the separate 24-shuffle 64-lane
// dsum reduction is gone (48 -> 27 epilogue shuffles).
// ---------------------------------------------------------------------------
#define FMA8(hv, p) do { \
  union { unsigned int i; float f; } c_; \
  c_.i = (hv).x << 16;          a0 += c_.f * (p); \
  c_.i = (hv).x & 0xffff0000u;  a1 += c_.f * (p); \
  c_.i = (hv).y << 16;          a2 += c_.f * (p); \
  c_.i = (hv).y & 0xffff0000u;  a3 += c_.f * (p); \
  c_.i = (hv).z << 16;          a4 += c_.f * (p); \
  c_.i = (hv).z & 0xffff0000u;  a5 += c_.f * (p); \
  c_.i = (hv).w << 16;          a6 += c_.f * (p); \
  c_.i = (hv).w & 0xffff0000u;  a7 += c_.f * (p); \
} while (0)

__global__ __launch_bounds__(256) void gat_agg(
    const int* __restrict__ csrsrc, const int* __restrict__ rowoff,
    const float4* __restrict__ el4, const float4* __restrict__ er4,
    const ushort_t* __restrict__ hbf, const float* __restrict__ gmaxM,
    float* __restrict__ out, int N)
{
  __shared__ float sP[4 * 64 * 4];
  __shared__ int sS[4 * 64];
  const int t = threadIdx.x;
  const int l = t & 63;
  const int w = t >> 6;
  const int n = blockIdx.x * 4 + w;
  if (n >= N) return;
  const int rg = l >> 3;        // row group: which of 8 edge-rows I help load
  const int cg = l & 7;         // col group: feats cg*8..cg*8+7
  const int hd2 = cg >> 1;      // head of those 8 feats (never crosses a head)
  const int start = rowoff[n];
  const int end = rowoff[n + 1];
  const float M = gmaxM[0];
  const float4 ern = er4[n];
  float* sPw = sP + w * 256;
  int* sSw = sS + w * 64;
  const ushort_t* hcg = hbf + cg * 8;   // my 16B slice of any row

  float a0 = 0.f, a1 = 0.f, a2 = 0.f, a3 = 0.f;
  float a4 = 0.f, a5 = 0.f, a6 = 0.f, a7 = 0.f;
  float a8 = 0.f;   // denominator partial: sum of p over my row-groups, head hd2

  for (int base = start; base < end; base += 64) {
    const int cnt = min(64, end - base);
    int sn = 0;
    float4 pv = make_float4(0.f, 0.f, 0.f, 0.f);
    if (l < cnt) {
      sn = csrsrc[base + l];
      const float4 a = el4[sn];
      pv.x = __expf(leaky(a.x + ern.x) - M);
      pv.y = __expf(leaky(a.y + ern.y) - M);
      pv.z = __expf(leaky(a.z + ern.z) - M);
      pv.w = __expf(leaky(a.w + ern.w) - M);
    }
    *(float4*)(sPw + l * 4) = pv;   // lanes >= cnt store p=0 (kills pad rows)
    sSw[l] = sn;                    // lanes >= cnt store row 0 (harmless, p=0)

    // two octets (16 edge-rows) per iteration -> 2 dwordx4 gathers in flight
    for (int j = 0; j < cnt; j += 16) {
      const int sA = sSw[j + rg];
      const int sB = sSw[j + 8 + rg];          // always < 64, p=0 past cnt
      const float pA = sPw[(j + rg) * 4 + hd2];
      const float pB = sPw[(j + 8 + rg) * 4 + hd2];
      const uint4 hA = *(const uint4*)(hcg + (size_t)sA * 64);
      const uint4 hB = *(const uint4*)(hcg + (size_t)sB * 64);
      FMA8(hA, pA);
      FMA8(hB, pB);
      a8 += pA + pB;
    }
  }

  // combine the 8 row-group partials (lanes sharing cg: l, l^8, l^16, l^32);
  // a8 reduces to the full per-head denominator in the same rounds
  #pragma unroll
  for (int o = 8; o <= 32; o <<= 1) {
    a0 += __shfl_xor(a0, o, 64); a1 += __shfl_xor(a1, o, 64);
    a2 += __shfl_xor(a2, o, 64); a3 += __shfl_xor(a3, o, 64);
    a4 += __shfl_xor(a4, o, 64); a5 += __shfl_xor(a5, o, 64);
    a6 += __shfl_xor(a6, o, 64); a7 += __shfl_xor(a7, o, 64);
    a8 += __shfl_xor(a8, o, 64);
  }
  if (rg == 0) {   // lanes 0..7 write 32B each -> 256B contiguous per wave
    const float r = 1.0f / (a8 + 1e-16f);
    float4* orow = (float4*)(out + (size_t)n * 64 + cg * 8);
    orow[0] = make_float4(a0 * r, a1 * r, a2 * r, a3 * r);
    orow[1] = make_float4(a4 * r, a5 * r, a6 * r, a7 * r);
  }
}

// ---------------------------------------------------------------------------
extern "C" void kernel_launch(void* const* d_in, const int* in_sizes, int n_in,
                              void* d_out, int out_size, void* d_ws, size_t ws_size,
                              hipStream_t stream) {
  const float* feat  = (const float*)d_in[0];
  const float* W     = (const float*)d_in[1];
  const float* attnl = (const float*)d_in[2];
  const float* attnr = (const float*)d_in[3];
  const int* src = (const int*)d_in[4];
  const int* trg = (const int*)d_in[5];
  float* out = (float*)d_out;

  const int N = in_sizes[0] / 128;  // 100000
  const int E = in_sizes[4];        // 1600000

  const int nbL  = (N + 63) / 64;        // 1563 linear blocks
  const int nbkt = (N + 511) >> 9;       // 196 coarse buckets

  char* p = (char*)d_ws;
  auto take = [&](size_t bytes) -> char* {
    char* r = p;
    p += (bytes + 255) & ~(size_t)255;
    return r;
  };
  // fixed buffers first, then size blockHist to whatever space remains
  ushort_t* h_bf  = (ushort_t*)take((size_t)N * 64 * 2); // 12.8 MB
  float* el       = (float*)take((size_t)N * 16);        // 1.6 MB
  float* er       = (float*)take((size_t)N * 16);        // 1.6 MB
  int* rowoff     = (int*)take((size_t)(N + 1) * 4);
  int* csrsrc     = (int*)take((size_t)E * 4);           // 6.4 MB
  unsigned int* binned = (unsigned int*)take((size_t)E * 4); // 6.4 MB
  ushort_t* wfrag = (ushort_t*)take(5 * 4 * 64 * 8 * 2); // 20.5 KB
  int* colTotal   = (int*)take((size_t)nbkt * 4);
  int* bucketBase = (int*)take((size_t)(nbkt + 1) * 4);
  float* blockmax2 = (float*)take((size_t)nbL * 2 * 4);
  float* gmaxM    = (float*)take(256);

  // workspace-safe sort-block count: target 800 blocks (fills 256 CUs),
  // degrade gracefully toward the proven ~200-block config if ws is tight
  const size_t used = (size_t)(p - (char*)d_ws);
  const size_t avail = (ws_size > used + 512) ? (ws_size - used - 512) : 0;
  int nb3 = (int)(avail / ((size_t)nbkt * 4));
  if (nb3 > 800) nb3 = 800;
  if (nb3 < 64) nb3 = 64;
  int epb = (E + nb3 - 1) / nb3;
  nb3 = (E + epb - 1) / epb;             // drop empty tail blocks
  int* blockHist  = (int*)take((size_t)nb3 * nbkt * 4);

  packw_hist<<<nb3 + 1, 256, 0, stream>>>(W, attnl, attnr, wfrag,
                                          trg, E, nbkt, blockHist, nb3, epb);
  bucket_scan<<<nbkt, 64, 0, stream>>>(blockHist, nb3, nbkt, colTotal);
  bucket_base<<<1, 64, 0, stream>>>(colTotal, nbkt, bucketBase, rowoff, N, E);
  bucket_scatter<<<nb3, 256, 0, stream>>>(src, trg, E, nbkt, blockHist,
                                          bucketBase, binned, epb);
  gat_linear<<<nbL, 256, 0, stream>>>(feat, wfrag, h_bf, el, er,
                                      blockmax2, N);
  fine_scatter<<<nbkt, 512, 0, stream>>>(binned, bucketBase, rowoff, csrsrc,
                                         N, blockmax2, nbL, gmaxM);
  gat_agg<<<(N + 3) / 4, 256, 0, stream>>>(csrsrc, rowoff, (const float4*)el,
                                           (const float4*)er, h_bf,
                                           gmaxM, out, N);
}

// Round 6
// 202.520 us; speedup vs baseline: 1.1054x; 1.0085x over previous
//
#include <hip/hip_runtime.h>

typedef unsigned short ushort_t;
typedef __attribute__((ext_vector_type(8))) short bf16x8;
typedef __attribute__((ext_vector_type(4))) float f32x4v;

static __device__ __forceinline__ float bf2f(ushort_t u) {
  union { unsigned int i; float f; } v; v.i = ((unsigned int)u) << 16; return v.f;
}
static __device__ __forceinline__ ushort_t f2bf(float f) {
  union { float f; unsigned int i; } v; v.f = f;
  unsigned int r = v.i + 0x7FFFu + ((v.i >> 16) & 1u);
  return (ushort_t)(r >> 16);
}
static __device__ __forceinline__ float leaky(float s) {
  return s > 0.f ? s : 0.2f * s;
}

// ---------------------------------------------------------------------------
// FUSED: block nb3 packs W_ext into B-fragments; blocks 0..nb3-1 do the
// coarse-bucket histogram. epb is runtime (workspace-sized).
// ---------------------------------------------------------------------------
__global__ __launch_bounds__(256) void packw_hist(
    const float* __restrict__ W, const float* __restrict__ attnl,
    const float* __restrict__ attnr, ushort_t* __restrict__ wfrag,
    const int* __restrict__ trg, int E, int nbkt,
    int* __restrict__ blockHist, int nb3, int epb)
{
  const int b = blockIdx.x;
  const int t = threadIdx.x;
  if (b == nb3) {
    const int kc = t >> 6, l = t & 63;
    const int q = l >> 4, n = l & 15;
    #pragma unroll
    for (int tile = 0; tile < 5; ++tile) {
      #pragma unroll
      for (int j = 0; j < 8; ++j) {
        const int k = kc * 32 + q * 8 + j;
        float v = 0.f;
        if (tile < 4) {
          v = W[k * 64 + tile * 16 + n];
        } else if (n < 4) {
          for (int f = 0; f < 16; ++f)
            v += W[k * 64 + n * 16 + f] * attnl[n * 16 + f];
        } else if (n < 8) {
          const int hd = n - 4;
          for (int f = 0; f < 16; ++f)
            v += W[k * 64 + hd * 16 + f] * attnr[hd * 16 + f];
        }
        wfrag[((tile * 4 + kc) * 64 + l) * 8 + j] = f2bf(v);
      }
    }
    return;
  }
  __shared__ int hist[256];
  hist[t] = 0;
  __syncthreads();
  const int start = b * epb;
  const int end = min(start + epb, E);
  for (int e = start + t; e < end; e += 256)
    atomicAdd(&hist[trg[e] >> 9], 1);
  __syncthreads();
  if (t < nbkt) blockHist[b * nbkt + t] = hist[t];
}

// ---------------------------------------------------------------------------
// Per-bucket column scan of blockHist -> in-place exclusive prefix + total.
// ---------------------------------------------------------------------------
__global__ __launch_bounds__(64) void bucket_scan(
    int* __restrict__ blockHist, int nb3, int nbkt, int* __restrict__ colTotal)
{
  const int b = blockIdx.x;
  const int l = threadIdx.x;
  int carry = 0;
  for (int r = 0; r * 64 < nb3; ++r) {
    const int i = r * 64 + l;
    int v = (i < nb3) ? blockHist[i * nbkt + b] : 0;
    int incl = v;
    #pragma unroll
    for (int d = 1; d < 64; d <<= 1) {
      int u = __shfl_up(incl, d, 64);
      if (l >= d) incl += u;
    }
    if (i < nb3) blockHist[i * nbkt + b] = carry + incl - v;
    carry += __shfl(incl, 63, 64);
  }
  if (l == 0) colTotal[b] = carry;
}

// ---------------------------------------------------------------------------
// Scan colTotal -> bucketBase; rowoff[N]=E.
// ---------------------------------------------------------------------------
__global__ __launch_bounds__(64) void bucket_base(
    const int* __restrict__ colTotal, int nbkt, int* __restrict__ bucketBase,
    int* __restrict__ rowoff, int N, int E)
{
  const int l = threadIdx.x;
  int carry = 0;
  for (int r = 0; r * 64 < nbkt; ++r) {
    const int i = r * 64 + l;
    int v = (i < nbkt) ? colTotal[i] : 0;
    int incl = v;
    #pragma unroll
    for (int d = 1; d < 64; d <<= 1) {
      int u = __shfl_up(incl, d, 64);
      if (l >= d) incl += u;
    }
    if (i < nbkt) bucketBase[i] = carry + incl - v;
    carry += __shfl(incl, 63, 64);
  }
  if (l == 0) { bucketBase[nbkt] = carry; rowoff[N] = E; }
}

// ---------------------------------------------------------------------------
// Deterministic coarse scatter (no global atomics); payload (src<<9)|localTrg.
// ---------------------------------------------------------------------------
__global__ __launch_bounds__(256) void bucket_scatter(
    const int* __restrict__ src, const int* __restrict__ trg, int E, int nbkt,
    const int* __restrict__ blockHist, const int* __restrict__ bucketBase,
    unsigned int* __restrict__ binned, int epb)
{
  __shared__ int cursor[256];
  const int t = threadIdx.x, b = blockIdx.x;
  if (t < nbkt) cursor[t] = bucketBase[t] + blockHist[b * nbkt + t];
  __syncthreads();
  const int start = b * epb;
  const int end = min(start + epb, E);
  for (int e = start + t; e < end; e += 256) {
    const int ti = trg[e];
    const int bkt = ti >> 9;
    const int pos = atomicAdd(&cursor[bkt], 1);
    binned[pos] = ((unsigned int)src[e] << 9) | (unsigned int)(ti & 511);
  }
}

// ---------------------------------------------------------------------------
// Kernel A (MFMA): h_ext = feat @ W_ext. 64 nodes/block; wave w owns nodes
// w*16..w*16+15 across all 5 col-tiles. feat staged bf16 in LDS (pad 136).
// Tile 4 yields el/er directly in C-layout -> no shuffle reductions.
// ---------------------------------------------------------------------------
__global__ __launch_bounds__(256) void gat_linear(
    const float* __restrict__ feat, const ushort_t* __restrict__ wfrag,
    ushort_t* __restrict__ h_out, float* __restrict__ el, float* __restrict__ er,
    float* __restrict__ blockmax2, int N)
{
  __shared__ ushort_t sFb[64 * 136];   // 17.4 KB
  __shared__ float wmax[8];
  const int t = threadIdx.x;
  const int b = blockIdx.x;
  const int w = t >> 6, l = t & 63;
  const int q = l >> 4, m = l & 15;

  // stage feat (64 x 128 fp32 -> bf16), coalesced float4 loads
  const float4* gF = (const float4*)(feat + (size_t)b * 64 * 128);
  #pragma unroll
  for (int i = 0; i < 8; ++i) {
    const int idx = i * 256 + t;
    const int node = idx >> 5, off = idx & 31;
    float4 v = make_float4(0.f, 0.f, 0.f, 0.f);
    if (b * 64 + node < N) v = gF[idx];
    unsigned int p0 = ((unsigned int)f2bf(v.y) << 16) | f2bf(v.x);
    unsigned int p1 = ((unsigned int)f2bf(v.w) << 16) | f2bf(v.z);
    *(uint2*)(sFb + node * 136 + off * 4) = make_uint2(p0, p1);
  }
  __syncthreads();

  // A-fragments: 4 K-chunks, one ds_read_b128 each
  bf16x8 a[4];
  const ushort_t* arow = sFb + (w * 16 + m) * 136 + q * 8;
  #pragma unroll
  for (int kc = 0; kc < 4; ++kc)
    a[kc] = *(const bf16x8*)(arow + kc * 32);

  // tiles 0..3: h columns
  #pragma unroll
  for (int tile = 0; tile < 4; ++tile) {
    f32x4v acc = {0.f, 0.f, 0.f, 0.f};
    #pragma unroll
    for (int kc = 0; kc < 4; ++kc) {
      bf16x8 bfr = *(const bf16x8*)(wfrag + ((tile * 4 + kc) * 64 + l) * 8);
      acc = __builtin_amdgcn_mfma_f32_16x16x32_bf16(a[kc], bfr, acc, 0, 0, 0);
    }
    #pragma unroll
    for (int r = 0; r < 4; ++r) {
      const int gn = b * 64 + w * 16 + q * 4 + r;
      if (gn < N) h_out[(size_t)gn * 64 + tile * 16 + m] = f2bf(acc[r]);
    }
  }

  // tile 4: el (cols 0-3) / er (cols 4-7)
  f32x4v acc4 = {0.f, 0.f, 0.f, 0.f};
  #pragma unroll
  for (int kc = 0; kc < 4; ++kc) {
    bf16x8 bfr = *(const bf16x8*)(wfrag + ((4 * 4 + kc) * 64 + l) * 8);
    acc4 = __builtin_amdgcn_mfma_f32_16x16x32_bf16(a[kc], bfr, acc4, 0, 0, 0);
  }
  float mel = -1e30f, mer = -1e30f;
  #pragma unroll
  for (int r = 0; r < 4; ++r) {
    const int gn = b * 64 + w * 16 + q * 4 + r;
    const float v = acc4[r];
    if (m < 4) {
      if (gn < N) el[gn * 4 + m] = v;
      mel = fmaxf(mel, v);
    } else if (m < 8) {
      if (gn < N) er[gn * 4 + (m - 4)] = v;
      mer = fmaxf(mer, v);
    }
  }
  #pragma unroll
  for (int o = 1; o <= 32; o <<= 1) {
    mel = fmaxf(mel, __shfl_xor(mel, o, 64));
    mer = fmaxf(mer, __shfl_xor(mer, o, 64));
  }
  if (l == 0) { wmax[w * 2] = mel; wmax[w * 2 + 1] = mer; }
  __syncthreads();
  if (t == 0) {
    float aa = fmaxf(fmaxf(wmax[0], wmax[2]), fmaxf(wmax[4], wmax[6]));
    float cc = fmaxf(fmaxf(wmax[1], wmax[3]), fmaxf(wmax[5], wmax[7]));
    blockmax2[b * 2] = aa;
    blockmax2[b * 2 + 1] = cc;
  }
}

// ---------------------------------------------------------------------------
// Fine sort (one block per bucket) + block 0 reduces blockmax2 -> gmaxM.
// ---------------------------------------------------------------------------
__global__ __launch_bounds__(512) void fine_scatter(
    const unsigned int* __restrict__ binned, const int* __restrict__ bucketBase,
    int* __restrict__ rowoff, int* __restrict__ csrsrc, int N,
    const float* __restrict__ blockmax2, int nbL, float* __restrict__ gmaxM)
{
  __shared__ int cnt[512];
  __shared__ int ws[8];
  __shared__ float wmg[16];
  const int t = threadIdx.x, b = blockIdx.x;
  const int l = t & 63, w = t >> 6;
  const int base = bucketBase[b];
  const int end = bucketBase[b + 1];
  cnt[t] = 0;
  if (b == 0) {
    float mel = -1e30f, mer = -1e30f;
    for (int i = t; i < nbL; i += 512) {
      mel = fmaxf(mel, blockmax2[i * 2]);
      mer = fmaxf(mer, blockmax2[i * 2 + 1]);
    }
    #pragma unroll
    for (int o = 1; o <= 32; o <<= 1) {
      mel = fmaxf(mel, __shfl_xor(mel, o, 64));
      mer = fmaxf(mer, __shfl_xor(mer, o, 64));
    }
    if (l == 0) { wmg[w * 2] = mel; wmg[w * 2 + 1] = mer; }
  }
  __syncthreads();
  if (b == 0 && t == 0) {
    float aa = -1e30f, cc = -1e30f;
    for (int i = 0; i < 8; ++i) {
      aa = fmaxf(aa, wmg[i * 2]);
      cc = fmaxf(cc, wmg[i * 2 + 1]);
    }
    gmaxM[0] = fmaxf(0.f, aa + cc);
  }
  for (int i = base + t; i < end; i += 512)
    atomicAdd(&cnt[binned[i] & 511u], 1);
  __syncthreads();
  const int v = cnt[t];
  int incl = v;
  #pragma unroll
  for (int d = 1; d < 64; d <<= 1) {
    int u = __shfl_up(incl, d, 64);
    if (l >= d) incl += u;
  }
  if (l == 63) ws[w] = incl;
  __syncthreads();
  int woff = 0;
  for (int i = 0; i < w; ++i) woff += ws[i];
  const int loc = woff + incl - v;
  cnt[t] = loc;
  const int gt = b * 512 + t;
  if (gt < N) rowoff[gt] = base + loc;
  __syncthreads();
  for (int i = base + t; i < end; i += 512) {
    const unsigned int pv = binned[i];
    const int lt = (int)(pv & 511u);
    const int pos = base + atomicAdd(&cnt[lt], 1);
    csrsrc[pos] = (int)(pv >> 9);
  }
}

// ---------------------------------------------------------------------------
// Aggregation: FOUR nodes per wave. Lanes 16k..16k+15 stage node k's next 16
// edges (exp phase ~full lane utilization vs 25% before). Inner loop: lane
// (rg=l>>3, cg=l&7); per j-iter A-side gathers nodes 0/1 (rg>>2), B-side
// nodes 2/3, each lane one dwordx4 = 8 h-cols of one edge-row. Separate
// accumulators aA/aB + denominators dA/dB. Reduction: xor o=8,16 ONLY
// (o=32 would mix nodes) -> 36 shuffles per 4 nodes (9/node vs 27/node).
// er-row load hoisted out of the chunk loop (loop-invariant).
// ---------------------------------------------------------------------------
#define UNPACK_FMA(hv, p, acc) do { \
  union { unsigned int i; float f; } c_; \
  c_.i = (hv).x << 16;          acc[0] += c_.f * (p); \
  c_.i = (hv).x & 0xffff0000u;  acc[1] += c_.f * (p); \
  c_.i = (hv).y << 16;          acc[2] += c_.f * (p); \
  c_.i = (hv).y & 0xffff0000u;  acc[3] += c_.f * (p); \
  c_.i = (hv).z << 16;          acc[4] += c_.f * (p); \
  c_.i = (hv).z & 0xffff0000u;  acc[5] += c_.f * (p); \
  c_.i = (hv).w << 16;          acc[6] += c_.f * (p); \
  c_.i = (hv).w & 0xffff0000u;  acc[7] += c_.f * (p); \
} while (0)

__global__ __launch_bounds__(256) void gat_agg(
    const int* __restrict__ csrsrc, const int* __restrict__ rowoff,
    const float4* __restrict__ el4, const float4* __restrict__ er4,
    const ushort_t* __restrict__ hbf, const float* __restrict__ gmaxM,
    float* __restrict__ out, int N)
{
  __shared__ float sP[4 * 64 * 4];
  __shared__ int sS[4 * 64];
  const int t = threadIdx.x;
  const int l = t & 63;
  const int w = t >> 6;
  const int nbase = blockIdx.x * 16 + w * 4;   // this wave's 4 nodes
  const int rg = l >> 3;        // row group 0..7
  const int cg = l & 7;         // col group: feats cg*8..cg*8+7
  const int hd2 = cg >> 1;      // head of those 8 feats
  const int ks = l >> 4;        // staging node 0..3
  const int le = l & 15;        // staging edge slot
  const float M = gmaxM[0];
  float* sPw = sP + w * 256;
  int* sSw = sS + w * 64;
  const ushort_t* hcg = hbf + cg * 8;   // my 16B slice of any row

  // per-lane node bounds (clamped; node >= N -> rs == re -> zero work)
  const int nk = nbase + ks;
  const int rs = rowoff[min(nk, N)];
  const int re = rowoff[min(nk + 1, N)];
  const float4 ernk = (rs < re) ? er4[nk]
                                : make_float4(0.f, 0.f, 0.f, 0.f);
  int deg = re - rs;
  deg = max(deg, __shfl_xor(deg, 16, 64));
  deg = max(deg, __shfl_xor(deg, 32, 64));   // max degree of the 4 nodes
  const int chunks = (deg + 15) >> 4;

  float aA[8] = {0.f,0.f,0.f,0.f,0.f,0.f,0.f,0.f};
  float aB[8] = {0.f,0.f,0.f,0.f,0.f,0.f,0.f,0.f};
  float dA = 0.f, dB = 0.f;

  for (int c = 0; c < chunks; ++c) {
    // stage up to 16 edges per node: p (4 heads) + src id
    int sn = 0;
    float4 pv = make_float4(0.f, 0.f, 0.f, 0.f);
    const int ei = rs + c * 16 + le;
    if (ei < re) {
      sn = csrsrc[ei];
      const float4 a = el4[sn];
      pv.x = __expf(leaky(a.x + ernk.x) - M);
      pv.y = __expf(leaky(a.y + ernk.y) - M);
      pv.z = __expf(leaky(a.z + ernk.z) - M);
      pv.w = __expf(leaky(a.w + ernk.w) - M);
    }
    *(float4*)(sPw + l * 4) = pv;   // pad slots carry p=0
    sSw[l] = sn;                    // pad slots row 0 (valid mem, p=0)

    const int rem = min(deg - c * 16, 16);
    const int jmax = (rem + 3) >> 2;
    for (int j = 0; j < jmax; ++j) {
      // A-side: nodes 0/1 (rg>>2), B-side: nodes 2/3
      const int iA = ((rg >> 2) * 16) + (rg & 3) + j * 4;
      const int iB = iA + 32;
      const int sA = sSw[iA];
      const int sB = sSw[iB];
      const float pA = sPw[iA * 4 + hd2];
      const float pB = sPw[iB * 4 + hd2];
      const uint4 hA = *(const uint4*)(hcg + (size_t)sA * 64);
      const uint4 hB = *(const uint4*)(hcg + (size_t)sB * 64);
      UNPACK_FMA(hA, pA, aA);
      UNPACK_FMA(hB, pB, aB);
      dA += pA;
      dB += pB;
    }
  }

  // reduce over rg quads {0..3} / {4..7}: o=8 pairs rg, o=16 merges quads.
  // Never o=32 (would mix the node pair). After this, lanes 0..31 hold
  // node0 (aA) / node2 (aB); lanes 32..63 hold node1 (aA) / node3 (aB).
  #pragma unroll
  for (int o = 8; o <= 16; o <<= 1) {
    #pragma unroll
    for (int i = 0; i < 8; ++i) {
      aA[i] += __shfl_xor(aA[i], o, 64);
      aB[i] += __shfl_xor(aB[i], o, 64);
    }
    dA += __shfl_xor(dA, o, 64);
    dB += __shfl_xor(dB, o, 64);
  }
  if ((rg & 3) == 0) {   // lanes 0..7 (nodes 0,2) and 32..39 (nodes 1,3)
    const int nA = nbase + (rg >> 2);
    const int nB = nA + 2;
    const float rA = 1.0f / (dA + 1e-16f);
    const float rB = 1.0f / (dB + 1e-16f);
    if (nA < N) {
      float4* orow = (float4*)(out + (size_t)nA * 64 + cg * 8);
      orow[0] = make_float4(aA[0] * rA, aA[1] * rA, aA[2] * rA, aA[3] * rA);
      orow[1] = make_float4(aA[4] * rA, aA[5] * rA, aA[6] * rA, aA[7] * rA);
    }
    if (nB < N) {
      float4* orow = (float4*)(out + (size_t)nB * 64 + cg * 8);
      orow[0] = make_float4(aB[0] * rB, aB[1] * rB, aB[2] * rB, aB[3] * rB);
      orow[1] = make_float4(aB[4] * rB, aB[5] * rB, aB[6] * rB, aB[7] * rB);
    }
  }
}

// ---------------------------------------------------------------------------
extern "C" void kernel_launch(void* const* d_in, const int* in_sizes, int n_in,
                              void* d_out, int out_size, void* d_ws, size_t ws_size,
                              hipStream_t stream) {
  const float* feat  = (const float*)d_in[0];
  const float* W     = (const float*)d_in[1];
  const float* attnl = (const float*)d_in[2];
  const float* attnr = (const float*)d_in[3];
  const int* src = (const int*)d_in[4];
  const int* trg = (const int*)d_in[5];
  float* out = (float*)d_out;

  const int N = in_sizes[0] / 128;  // 100000
  const int E = in_sizes[4];        // 1600000

  const int nbL  = (N + 63) / 64;        // 1563 linear blocks
  const int nbkt = (N + 511) >> 9;       // 196 coarse buckets

  char* p = (char*)d_ws;
  auto take = [&](size_t bytes) -> char* {
    char* r = p;
    p += (bytes + 255) & ~(size_t)255;
    return r;
  };
  // fixed buffers first, then size blockHist to whatever space remains
  ushort_t* h_bf  = (ushort_t*)take((size_t)N * 64 * 2); // 12.8 MB
  float* el       = (float*)take((size_t)N * 16);        // 1.6 MB
  float* er       = (float*)take((size_t)N * 16);        // 1.6 MB
  int* rowoff     = (int*)take((size_t)(N + 1) * 4);
  int* csrsrc     = (int*)take((size_t)E * 4);           // 6.4 MB
  unsigned int* binned = (unsigned int*)take((size_t)E * 4); // 6.4 MB
  ushort_t* wfrag = (ushort_t*)take(5 * 4 * 64 * 8 * 2); // 20.5 KB
  int* colTotal   = (int*)take((size_t)nbkt * 4);
  int* bucketBase = (int*)take((size_t)(nbkt + 1) * 4);
  float* blockmax2 = (float*)take((size_t)nbL * 2 * 4);
  float* gmaxM    = (float*)take(256);

  // workspace-safe sort-block count: target 800 blocks (fills 256 CUs),
  // degrade gracefully toward the proven ~200-block config if ws is tight
  const size_t used = (size_t)(p - (char*)d_ws);
  const size_t avail = (ws_size > used + 512) ? (ws_size - used - 512) : 0;
  int nb3 = (int)(avail / ((size_t)nbkt * 4));
  if (nb3 > 800) nb3 = 800;
  if (nb3 < 64) nb3 = 64;
  int epb = (E + nb3 - 1) / nb3;
  nb3 = (E + epb - 1) / epb;             // drop empty tail blocks
  int* blockHist  = (int*)take((size_t)nb3 * nbkt * 4);

  packw_hist<<<nb3 + 1, 256, 0, stream>>>(W, attnl, attnr, wfrag,
                                          trg, E, nbkt, blockHist, nb3, epb);
  bucket_scan<<<nbkt, 64, 0, stream>>>(blockHist, nb3, nbkt, colTotal);
  bucket_base<<<1, 64, 0, stream>>>(colTotal, nbkt, bucketBase, rowoff, N, E);
  bucket_scatter<<<nb3, 256, 0, stream>>>(src, trg, E, nbkt, blockHist,
                                          bucketBase, binned, epb);
  gat_linear<<<nbL, 256, 0, stream>>>(feat, wfrag, h_bf, el, er,
                                      blockmax2, N);
  fine_scatter<<<nbkt, 512, 0, stream>>>(binned, bucketBase, rowoff, csrsrc,
                                         N, blockmax2, nbL, gmaxM);
  gat_agg<<<(N + 15) / 16, 256, 0, stream>>>(csrsrc, rowoff, (const float4*)el,
                                             (const float4*)er, h_bf,
                                             gmaxM, out, N);
}